// Round 9
// baseline (241.372 us; speedup 1.0000x reference)
//
#include <hip/hip_runtime.h>
#include <math.h>

#define TT 2048
#define HH 128
#define ROWS 4
#define SP 132   // activation LDS row stride (pad)
#define NB (TT / ROWS)  // 512 blocks = 2 per CU
#define KS 0.088388347648318447f  // 1/sqrt(128)

struct P {
    const float* emb; const int* start;
    const float* w_in; const float* b_in;
    const float* w_out; const float* b_out;
    const float* w_f; const float* b_f;
    const float* w_i; const float* b_i;
    const float* w_v; const float* b_v;
    const float* w_q; const float* b_q;
    const float* w_k; const float* b_k;
    const float* w_o; const float* b_o;
    const float* w_ff; const float* b_ff;
    float* out;
    float* e;
    float* k0; float* v0; float* q0; float* o0; float* aux0;
    float* k1; float* v1; float* q1; float* o1; float* aux1;
};

__device__ __forceinline__ float dot4(float4 a, float4 b) {
    return a.x * b.x + a.y * b.y + a.z * b.z + a.w * b.w;
}

// Load 2 weight rows (h0, h0+1), col quarter qq (32 cols at colbase+qq*32),
// chunk order rotated by 2*qq to de-conflict the LDS x-broadcasts.
__device__ __forceinline__ void loadW2(const float* __restrict__ wm, int ld, int h0,
                                       int colbase, int qq, float4* wA, float4* wB) {
    const float* b0 = wm + h0 * ld + colbase + qq * 32;
    const float* b1 = b0 + ld;
#pragma unroll
    for (int j = 0; j < 8; j++) {
        int off = ((j + 2 * qq) & 7) * 4;
        wA[j] = *(const float4*)(b0 + off);
        wB[j] = *(const float4*)(b1 + off);
    }
}

// acc{A,B}[r] += dot(w{A,B}, x[r][qq*32 .. +32])  -- x reads are rotated LDS broadcasts
__device__ __forceinline__ void gemv4x2(const float4* wA, const float4* wB,
        const float* __restrict__ xls, int qq, float* aA, float* aB) {
#pragma unroll
    for (int r = 0; r < ROWS; r++) {
        const float* x = xls + r * SP + qq * 32;
        float sA = 0.f, sB = 0.f;
#pragma unroll
        for (int j = 0; j < 8; j++) {
            int off = ((j + 2 * qq) & 7) * 4;
            float4 x4 = *(const float4*)(x + off);
            sA += dot4(x4, wA[j]);
            sB += dot4(x4, wB[j]);
        }
        aA[r] += sA;
        aB[r] += sB;
    }
}

// reduce partial sums across the 4 qq lanes (bits 0-1 of tid)
__device__ __forceinline__ void reduce4(float* a) {
#pragma unroll
    for (int r = 0; r < ROWS; r++) {
        a[r] += __shfl_xor(a[r], 1, 64);
        a[r] += __shfl_xor(a[r], 2, 64);
    }
}

// f/i gates: wave wv owns row wv (4 waves); writes aux[t] = {g, exp(i), startflag, 0}
__device__ __forceinline__ void gates(int t0, const float* __restrict__ xls,
        const float* __restrict__ wf, float bf, const float* __restrict__ wi, float bi,
        const int* __restrict__ start, float* __restrict__ aux) {
    int tid = threadIdx.x;
    int wv = tid >> 6, lane = tid & 63;
    const float* x = xls + wv * SP + 2 * lane;
    float pf = x[0] * wf[2 * lane] + x[1] * wf[2 * lane + 1];
    float pi = x[0] * wi[2 * lane] + x[1] * wi[2 * lane + 1];
#pragma unroll
    for (int off = 1; off <= 32; off <<= 1) {
        pf += __shfl_xor(pf, off, 64);
        pi += __shfl_xor(pi, off, 64);
    }
    if (lane == 0) {
        int t = t0 + wv;
        int st = start[t];
        float gg = st ? 0.f : 1.f / (1.f + expf(-(pf + bf)));
        *(float4*)(aux + t * 4) = make_float4(gg, expf(pi + bi), st ? 1.f : 0.f, 0.f);
    }
}

// mLSTM attention: wave wv owns row t0+wv; backward walk within episode segment.
__device__ __forceinline__ void attn_phase(int t0,
        const float* __restrict__ kb, const float* __restrict__ vb,
        const float* __restrict__ qb, const float* __restrict__ ob,
        const float* __restrict__ aux, float* __restrict__ hsb) {
    int tid = threadIdx.x;
    int wv = tid >> 6, lane = tid & 63;
    int t = t0 + wv;
    float2 q2 = *(const float2*)(qb + t * HH + 2 * lane);
    float nx = 0.f, ny = 0.f, dsum = 0.f, decay = 1.f;
    int tp = t;
    float2 k2 = *(const float2*)(kb + tp * HH + 2 * lane);
    float2 v2 = *(const float2*)(vb + tp * HH + 2 * lane);
    float4 a4 = *(const float4*)(aux + tp * 4);  // {g, iexp, startflag, 0}
    while (true) {
        int tn = (tp > 0) ? tp - 1 : 0;
        float2 k2n = *(const float2*)(kb + tn * HH + 2 * lane);
        float2 v2n = *(const float2*)(vb + tn * HH + 2 * lane);
        float4 a4n = *(const float4*)(aux + tn * 4);
        float pp = k2.x * q2.x + k2.y * q2.y;
#pragma unroll
        for (int off = 1; off <= 32; off <<= 1) pp += __shfl_xor(pp, off, 64);
        float coeff = decay * a4.y * pp;
        nx += coeff * v2.x; ny += coeff * v2.y;
        dsum += coeff;
        if (tp == 0 || a4.z != 0.f) break;
        decay *= a4.x;
        tp = tn; k2 = k2n; v2 = v2n; a4 = a4n;
    }
    float inv = 1.f / fmaxf(fabsf(dsum), 1.f);
    float2 o2 = *(const float2*)(ob + t * HH + 2 * lane);
    *(float2*)(hsb + wv * SP + 2 * lane) = make_float2(o2.x * nx * inv, o2.y * ny * inv);
}

// stage 4 activation rows global->LDS (threads 0..127)
__device__ __forceinline__ void stage_rows(const float* __restrict__ src, int t0,
                                           float* __restrict__ dst) {
    int tid = threadIdx.x;
    if (tid < 128) {
        int r = tid >> 5, c = (tid & 31) << 2;
        *(float4*)(dst + r * SP + c) = *(const float4*)(src + (t0 + r) * HH + c);
    }
}

// ---------------- K1: e = emb @ w_in.T + b; layer-0 proj (v,q,k,o,f,i) ----------------
__global__ __launch_bounds__(256, 2) void k1(P p) {
    __shared__ float xs[ROWS * SP];
    __shared__ float es[ROWS * SP];
    int tid = threadIdx.x;
    int t0 = blockIdx.x * ROWS;
    int qq = tid & 3, hp = tid >> 2, h0 = 2 * hp;
    stage_rows(p.emb, t0, xs);
    __syncthreads();
    float4 wA[8], wB[8];
    float aA[4], aB[4];
    // ---- e = emb @ w_in.T + b_in ----
    loadW2(p.w_in, 128, h0, 0, qq, wA, wB);
#pragma unroll
    for (int r = 0; r < 4; r++) { aA[r] = 0.f; aB[r] = 0.f; }
    gemv4x2(wA, wB, xs, qq, aA, aB);
    reduce4(aA); reduce4(aB);
    if (qq == 0) {
        float b0 = p.b_in[h0], b1 = p.b_in[h0 + 1];
#pragma unroll
        for (int r = 0; r < 4; r++) {
            float2 v = make_float2(aA[r] + b0, aB[r] + b1);
            *(float2*)(es + r * SP + h0) = v;
            *(float2*)(p.e + (t0 + r) * HH + h0) = v;
        }
    }
    __syncthreads();
    gates(t0, es, p.w_f, p.b_f[0], p.w_i, p.b_i[0], p.start, p.aux0);
    // ---- v0 ----
    loadW2(p.w_v, 128, h0, 0, qq, wA, wB);
#pragma unroll
    for (int r = 0; r < 4; r++) { aA[r] = 0.f; aB[r] = 0.f; }
    gemv4x2(wA, wB, es, qq, aA, aB);
    reduce4(aA); reduce4(aB);
    if (qq == 0) {
        float b0 = p.b_v[h0], b1 = p.b_v[h0 + 1];
#pragma unroll
        for (int r = 0; r < 4; r++)
            *(float2*)(p.v0 + (t0 + r) * HH + h0) = make_float2(aA[r] + b0, aB[r] + b1);
    }
    // ---- q0 ----
    loadW2(p.w_q, 128, h0, 0, qq, wA, wB);
#pragma unroll
    for (int r = 0; r < 4; r++) { aA[r] = 0.f; aB[r] = 0.f; }
    gemv4x2(wA, wB, es, qq, aA, aB);
    reduce4(aA); reduce4(aB);
    if (qq == 0) {
        float b0 = p.b_q[h0], b1 = p.b_q[h0 + 1];
#pragma unroll
        for (int r = 0; r < 4; r++)
            *(float2*)(p.q0 + (t0 + r) * HH + h0) = make_float2(aA[r] + b0, aB[r] + b1);
    }
    // ---- k0 ----
    loadW2(p.w_k, 128, h0, 0, qq, wA, wB);
#pragma unroll
    for (int r = 0; r < 4; r++) { aA[r] = 0.f; aB[r] = 0.f; }
    gemv4x2(wA, wB, es, qq, aA, aB);
    reduce4(aA); reduce4(aB);
    if (qq == 0) {
        float b0 = p.b_k[h0], b1 = p.b_k[h0 + 1];
#pragma unroll
        for (int r = 0; r < 4; r++)
            *(float2*)(p.k0 + (t0 + r) * HH + h0) =
                make_float2(aA[r] * KS + b0, aB[r] * KS + b1);
    }
    // ---- o0 ----
    loadW2(p.w_o, 128, h0, 0, qq, wA, wB);
#pragma unroll
    for (int r = 0; r < 4; r++) { aA[r] = 0.f; aB[r] = 0.f; }
    gemv4x2(wA, wB, es, qq, aA, aB);
    reduce4(aA); reduce4(aB);
    if (qq == 0) {
        float b0 = p.b_o[h0], b1 = p.b_o[h0 + 1];
#pragma unroll
        for (int r = 0; r < 4; r++)
            *(float2*)(p.o0 + (t0 + r) * HH + h0) = make_float2(
                1.f / (1.f + expf(-(aA[r] + b0))), 1.f / (1.f + expf(-(aB[r] + b1))));
    }
}

// ---------------- K2: attn0 + ff0 + layer-1 proj ----------------
__global__ __launch_bounds__(256, 2) void k2(P p) {
    __shared__ float es[ROWS * SP];
    __shared__ float hs[ROWS * SP];
    __shared__ float zs[ROWS * SP];
    int tid = threadIdx.x;
    int t0 = blockIdx.x * ROWS;
    int qq = tid & 3, hp = tid >> 2, h0 = 2 * hp;
    stage_rows(p.e, t0, es);
    attn_phase(t0, p.k0, p.v0, p.q0, p.o0, p.aux0, hs);
    __syncthreads();
    float4 wA[8], wB[8];
    float aA[4], aB[4];
    // ---- ff0: cols [0,128) x hs, then cols [128,256) x es; lrelu -> zs ----
    loadW2(p.w_ff, 256, h0, 0, qq, wA, wB);
#pragma unroll
    for (int r = 0; r < 4; r++) { aA[r] = 0.f; aB[r] = 0.f; }
    gemv4x2(wA, wB, hs, qq, aA, aB);
    loadW2(p.w_ff, 256, h0, 128, qq, wA, wB);
    gemv4x2(wA, wB, es, qq, aA, aB);
    reduce4(aA); reduce4(aB);
    if (qq == 0) {
        float b0 = p.b_ff[h0], b1 = p.b_ff[h0 + 1];
#pragma unroll
        for (int r = 0; r < 4; r++) {
            float z0 = aA[r] + b0, z1 = aB[r] + b1;
            z0 = z0 > 0.f ? z0 : 0.01f * z0;
            z1 = z1 > 0.f ? z1 : 0.01f * z1;
            *(float2*)(zs + r * SP + h0) = make_float2(z0, z1);
        }
    }
    __syncthreads();
    gates(t0, zs, p.w_f + HH, p.b_f[1], p.w_i + HH, p.b_i[1], p.start, p.aux1);
    // ---- v1 ----
    loadW2(p.w_v + HH * HH, 128, h0, 0, qq, wA, wB);
#pragma unroll
    for (int r = 0; r < 4; r++) { aA[r] = 0.f; aB[r] = 0.f; }
    gemv4x2(wA, wB, zs, qq, aA, aB);
    reduce4(aA); reduce4(aB);
    if (qq == 0) {
        float b0 = p.b_v[HH + h0], b1 = p.b_v[HH + h0 + 1];
#pragma unroll
        for (int r = 0; r < 4; r++)
            *(float2*)(p.v1 + (t0 + r) * HH + h0) = make_float2(aA[r] + b0, aB[r] + b1);
    }
    // ---- q1 ----
    loadW2(p.w_q + HH * HH, 128, h0, 0, qq, wA, wB);
#pragma unroll
    for (int r = 0; r < 4; r++) { aA[r] = 0.f; aB[r] = 0.f; }
    gemv4x2(wA, wB, zs, qq, aA, aB);
    reduce4(aA); reduce4(aB);
    if (qq == 0) {
        float b0 = p.b_q[HH + h0], b1 = p.b_q[HH + h0 + 1];
#pragma unroll
        for (int r = 0; r < 4; r++)
            *(float2*)(p.q1 + (t0 + r) * HH + h0) = make_float2(aA[r] + b0, aB[r] + b1);
    }
    // ---- k1 ----
    loadW2(p.w_k + HH * HH, 128, h0, 0, qq, wA, wB);
#pragma unroll
    for (int r = 0; r < 4; r++) { aA[r] = 0.f; aB[r] = 0.f; }
    gemv4x2(wA, wB, zs, qq, aA, aB);
    reduce4(aA); reduce4(aB);
    if (qq == 0) {
        float b0 = p.b_k[HH + h0], b1 = p.b_k[HH + h0 + 1];
#pragma unroll
        for (int r = 0; r < 4; r++)
            *(float2*)(p.k1 + (t0 + r) * HH + h0) =
                make_float2(aA[r] * KS + b0, aB[r] * KS + b1);
    }
    // ---- o1 ----
    loadW2(p.w_o + HH * HH, 128, h0, 0, qq, wA, wB);
#pragma unroll
    for (int r = 0; r < 4; r++) { aA[r] = 0.f; aB[r] = 0.f; }
    gemv4x2(wA, wB, zs, qq, aA, aB);
    reduce4(aA); reduce4(aB);
    if (qq == 0) {
        float b0 = p.b_o[HH + h0], b1 = p.b_o[HH + h0 + 1];
#pragma unroll
        for (int r = 0; r < 4; r++)
            *(float2*)(p.o1 + (t0 + r) * HH + h0) = make_float2(
                1.f / (1.f + expf(-(aA[r] + b0))), 1.f / (1.f + expf(-(aB[r] + b1))));
    }
}

// ---------------- K3: attn1 + ff1 + final dense ----------------
__global__ __launch_bounds__(256, 2) void k3(P p) {
    __shared__ float es[ROWS * SP];
    __shared__ float hs[ROWS * SP];
    __shared__ float zs[ROWS * SP];
    int tid = threadIdx.x;
    int t0 = blockIdx.x * ROWS;
    int qq = tid & 3, hp = tid >> 2, h0 = 2 * hp;
    stage_rows(p.e, t0, es);
    attn_phase(t0, p.k1, p.v1, p.q1, p.o1, p.aux1, hs);
    __syncthreads();
    const float* wff1 = p.w_ff + HH * 2 * HH;
    float4 wA[8], wB[8];
    float aA[4], aB[4];
    // ---- ff1 ----
    loadW2(wff1, 256, h0, 0, qq, wA, wB);
#pragma unroll
    for (int r = 0; r < 4; r++) { aA[r] = 0.f; aB[r] = 0.f; }
    gemv4x2(wA, wB, hs, qq, aA, aB);
    loadW2(wff1, 256, h0, 128, qq, wA, wB);
    gemv4x2(wA, wB, es, qq, aA, aB);
    reduce4(aA); reduce4(aB);
    if (qq == 0) {
        float b0 = p.b_ff[HH + h0], b1 = p.b_ff[HH + h0 + 1];
#pragma unroll
        for (int r = 0; r < 4; r++) {
            float z0 = aA[r] + b0, z1 = aB[r] + b1;
            z0 = z0 > 0.f ? z0 : 0.01f * z0;
            z1 = z1 > 0.f ? z1 : 0.01f * z1;
            *(float2*)(zs + r * SP + h0) = make_float2(z0, z1);
        }
    }
    __syncthreads();
    // ---- out = zs @ w_out.T + b_out ----
    loadW2(p.w_out, 128, h0, 0, qq, wA, wB);
#pragma unroll
    for (int r = 0; r < 4; r++) { aA[r] = 0.f; aB[r] = 0.f; }
    gemv4x2(wA, wB, zs, qq, aA, aB);
    reduce4(aA); reduce4(aB);
    if (qq == 0) {
        float b0 = p.b_out[h0], b1 = p.b_out[h0 + 1];
#pragma unroll
        for (int r = 0; r < 4; r++)
            *(float2*)(p.out + (t0 + r) * HH + h0) = make_float2(aA[r] + b0, aB[r] + b1);
    }
}

extern "C" void kernel_launch(void* const* d_in, const int* in_sizes, int n_in,
                              void* d_out, int out_size, void* d_ws, size_t ws_size,
                              hipStream_t stream) {
    P p;
    p.emb   = (const float*)d_in[0];
    p.start = (const int*)  d_in[1];
    p.w_in  = (const float*)d_in[2];
    p.b_in  = (const float*)d_in[3];
    p.w_out = (const float*)d_in[4];
    p.b_out = (const float*)d_in[5];
    p.w_f   = (const float*)d_in[6];
    p.b_f   = (const float*)d_in[7];
    p.w_i   = (const float*)d_in[8];
    p.b_i   = (const float*)d_in[9];
    p.w_v   = (const float*)d_in[10];
    p.b_v   = (const float*)d_in[11];
    p.w_q   = (const float*)d_in[12];
    p.b_q   = (const float*)d_in[13];
    p.w_k   = (const float*)d_in[14];
    p.b_k   = (const float*)d_in[15];
    p.w_o   = (const float*)d_in[16];
    p.b_o   = (const float*)d_in[17];
    p.w_ff  = (const float*)d_in[18];
    p.b_ff  = (const float*)d_in[19];
    p.out   = (float*)d_out;

    float* ws = (float*)d_ws;
    p.e    = ws; ws += TT * HH;
    p.k0   = ws; ws += TT * HH;
    p.v0   = ws; ws += TT * HH;
    p.q0   = ws; ws += TT * HH;
    p.o0   = ws; ws += TT * HH;
    p.k1   = ws; ws += TT * HH;
    p.v1   = ws; ws += TT * HH;
    p.q1   = ws; ws += TT * HH;
    p.o1   = ws; ws += TT * HH;
    p.aux0 = ws; ws += TT * 4;
    p.aux1 = ws; ws += TT * 4;

    k1<<<dim3(NB), dim3(256), 0, stream>>>(p);
    k2<<<dim3(NB), dim3(256), 0, stream>>>(p);
    k3<<<dim3(NB), dim3(256), 0, stream>>>(p);
}